// Round 2
// baseline (557.337 us; speedup 1.0000x reference)
//
#include <hip/hip_runtime.h>

// Problem constants
#define HDIM 1024
#define SEQ  2048
#define BATCH 16
#define VOCAB 250002
#define M_TOT (BATCH * SEQ)                 // 32768 rows
#define SPARSE_OFF (BATCH * HDIM)           // 16384
#define COLBERT_OFF (SPARSE_OFF + BATCH * VOCAB)  // 4016416

typedef __attribute__((ext_vector_type(8))) short short8;   // 8 bf16 (4 VGPRs)
typedef __attribute__((ext_vector_type(4))) float f32x4;

static __device__ __forceinline__ unsigned short f2bf(float f) {
  union { float f; unsigned u; } v; v.f = f;
  unsigned r = v.u + 0x7fffu + ((v.u >> 16) & 1u);  // RNE
  return (unsigned short)(r >> 16);
}

// ---------------------------------------------------------------------------
// Kernel 1 (prep): blocks 0..1023 transpose+PACK W fp32(k,n) -> bf16 packed
// fragment-major Bp[(n16*32+K32)*512 + (q*16+n15)*8 + e]; a wave's MFMA
// B-fragment load is one contiguous 1 KB global_load_dwordx4 from the
// L2-resident 2 MB buffer. blocks 1024..1535 zero sparse region;
// 1536..1551 dense head.  (unchanged from round 1 — verified)
// ---------------------------------------------------------------------------
__global__ __launch_bounds__(256) void prep_kernel(
    const float* __restrict__ W, unsigned short* __restrict__ Wt,
    float* __restrict__ out, const float* __restrict__ hidden)
{
  __shared__ float tile[32][33];
  __shared__ float red[4];
  const int blk = blockIdx.x;
  if (blk < 1024) {
    const int n0 = (blk & 31) * 32, k0 = (blk >> 5) * 32;
    const int tx = threadIdx.x & 31, ty = threadIdx.x >> 5;   // 32 x 8
#pragma unroll
    for (int i = ty; i < 32; i += 8)
      tile[i][tx] = W[(size_t)(k0 + i) * HDIM + n0 + tx];
    __syncthreads();
#pragma unroll
    for (int i = ty; i < 32; i += 8) {
      const int n = n0 + i, k = k0 + tx;
      const size_t idx = (size_t)((n >> 4) * 32 + (k >> 5)) * 512
                       + (size_t)((((k >> 3) & 3) * 16 + (n & 15)) * 8 + (k & 7));
      Wt[idx] = f2bf(tile[tx][i]);
    }
  } else if (blk < 1536) {
    float4 z = {0.f, 0.f, 0.f, 0.f};
    float4* p = (float4*)(out + SPARSE_OFF);
    int idx = (blk - 1024) * 256 + threadIdx.x;
#pragma unroll 1
    for (; idx < 1000008; idx += 512 * 256) p[idx] = z;
  } else {
    const int b = blk - 1536;
    const int t = threadIdx.x;
    const float4* x = (const float4*)(hidden + (size_t)b * SEQ * HDIM);
    float4 v = x[t];
    float ss = v.x * v.x + v.y * v.y + v.z * v.z + v.w * v.w;
#pragma unroll
    for (int off = 32; off; off >>= 1) ss += __shfl_down(ss, off);
    if ((t & 63) == 0) red[t >> 6] = ss;
    __syncthreads();
    float tot = red[0] + red[1] + red[2] + red[3];
    float inv = 1.0f / fmaxf(sqrtf(tot), 1e-12f);
    v.x *= inv; v.y *= inv; v.z *= inv; v.w *= inv;
    ((float4*)(out + (size_t)b * HDIM))[t] = v;
  }
}

// ---------------------------------------------------------------------------
// Kernel 2 (fused, BM=128, two N-passes of 512 cols):
//  per pass: stage A fp32->bf16 into double-buffered swizzled LDS chunks
//  (K=64 each), B fragments register-loaded from L2-resident packed Wt
//  (read ONCE per block per pass -> 26 B/cyc/CU, half of round 1).
//  Pass 0: + sparse dot/scatter-max; store half raw; keep row SS in LDS.
//  Pass 1: finish SS locally, compute inv(mask,norm), store half normalized,
//  then re-read+scale+re-store pass-0's half (same block -> coherent).
// ---------------------------------------------------------------------------
#define ABUF_BYTES (128 * 64 * 2)          // 16 KB per K-chunk buffer
#define RED_OFF    (2 * ABUF_BYTES)        // 32 KB
#define FUSED_LDS  (RED_OFF + (128 * 8 + 128 + 128) * 4)

__global__ __launch_bounds__(512, 2) void fused_kernel(
    const float* __restrict__ hidden,
    const unsigned short* __restrict__ Bp,   // packed (1024,1024) bf16
    const float* __restrict__ bias,          // (1024,)
    const float* __restrict__ mask,          // (B, S)
    const float* __restrict__ sparse_W,      // (1024,)
    const float* __restrict__ sparse_b,      // (1,)
    const int* __restrict__ input_ids,       // (B*S,)
    float* __restrict__ out)
{
  extern __shared__ __align__(16) char smem[];
  float* redLDS = (float*)(smem + RED_OFF);     // [128][8]
  float* ssLDS  = redLDS + 128 * 8;             // [128]
  float* invLDS = ssLDS + 128;                  // [128]

  const int t = threadIdx.x;
  const int w = t >> 6, l = t & 63;
  const int q = l >> 4, ml = l & 15;
  const int mBase = blockIdx.x * 128;

  // staging map: thread -> (row, 16-float k-segment of the 64-chunk)
  const int srow = t >> 2;
  const int sseg = t & 3;
  const float* srcRow = hidden + (size_t)(mBase + srow) * HDIM + sseg * 16;
  const float* swRow  = sparse_W + sseg * 16;
  int wb0, wb1;
  {
    const int ks0 = sseg * 2, ks1 = ks0 + 1;
    wb0 = srow * 128 + ((((ks0 & 3) * 16) ^ ((srow & 3) << 4))
        + (((ks0 >> 2) ^ ((srow >> 2) & 1)) << 6));
    wb1 = srow * 128 + ((((ks1 & 3) * 16) ^ ((srow & 3) << 4))
        + (((ks1 >> 2) ^ ((srow >> 2) & 1)) << 6));
  }

  // A-fragment LDS read offsets (XOR bit6 with kk2 at use)
  int aoff0[8];
#pragma unroll
  for (int i = 0; i < 8; i++) {
    const int row = i * 16 + ml;
    aoff0[i] = row * 128 + (((q * 16) ^ ((row & 3) << 4)) + (((row >> 2) & 1) << 6));
  }

  float dot = 0.f;
  f32x4 sx[4];
  f32x4 acc[8][4];
  short8 af[8], bC[4], bN[4];
#pragma unroll
  for (int i = 0; i < 8; i++)
#pragma unroll
    for (int j = 0; j < 4; j++) acc[i][j] = (f32x4){0.f, 0.f, 0.f, 0.f};

#define SLOAD(KC) do {                                                   \
    _Pragma("unroll")                                                    \
    for (int h_ = 0; h_ < 4; h_++)                                       \
      sx[h_] = *(const f32x4*)(srcRow + (KC) * 64 + h_ * 4);             \
  } while (0)

#define SWRITE(BUFOFS, KC, DODOT) do {                                   \
    if (DODOT) {                                                         \
      _Pragma("unroll")                                                  \
      for (int h_ = 0; h_ < 4; h_++) {                                   \
        const f32x4 wv_ = *(const f32x4*)(swRow + (KC) * 64 + h_ * 4);   \
        dot = fmaf(sx[h_].x, wv_.x, dot); dot = fmaf(sx[h_].y, wv_.y, dot); \
        dot = fmaf(sx[h_].z, wv_.z, dot); dot = fmaf(sx[h_].w, wv_.w, dot); \
      }                                                                  \
    }                                                                    \
    short8 o0_, o1_;                                                     \
    o0_[0] = (short)f2bf(sx[0].x); o0_[1] = (short)f2bf(sx[0].y);        \
    o0_[2] = (short)f2bf(sx[0].z); o0_[3] = (short)f2bf(sx[0].w);        \
    o0_[4] = (short)f2bf(sx[1].x); o0_[5] = (short)f2bf(sx[1].y);        \
    o0_[6] = (short)f2bf(sx[1].z); o0_[7] = (short)f2bf(sx[1].w);        \
    o1_[0] = (short)f2bf(sx[2].x); o1_[1] = (short)f2bf(sx[2].y);        \
    o1_[2] = (short)f2bf(sx[2].z); o1_[3] = (short)f2bf(sx[2].w);        \
    o1_[4] = (short)f2bf(sx[3].x); o1_[5] = (short)f2bf(sx[3].y);        \
    o1_[6] = (short)f2bf(sx[3].z); o1_[7] = (short)f2bf(sx[3].w);        \
    *(short8*)(smem + (BUFOFS) + wb0) = o0_;                             \
    *(short8*)(smem + (BUFOFS) + wb1) = o1_;                             \
  } while (0)

#define LOADA(BUFOFS, KK2) do {                                          \
    _Pragma("unroll")                                                    \
    for (int i_ = 0; i_ < 8; i_++)                                       \
      af[i_] = *(const short8*)(smem + (BUFOFS) + (aoff0[i_] ^ ((KK2) << 6))); \
  } while (0)

#define LOADB(DST, K32) do {                                             \
    _Pragma("unroll")                                                    \
    for (int j_ = 0; j_ < 4; j_++)                                       \
      DST[j_] = *(const short8*)(Bpw + (size_t)((j_ * 32 + (K32)) * 512)); \
  } while (0)

#define MF(BF) do {                                                      \
    _Pragma("unroll")                                                    \
    for (int i_ = 0; i_ < 8; i_++)                                       \
      _Pragma("unroll")                                                  \
      for (int j_ = 0; j_ < 4; j_++)                                     \
        acc[i_][j_] = __builtin_amdgcn_mfma_f32_16x16x32_bf16(           \
            af[i_], BF[j_], acc[i_][j_], 0, 0, 0);                       \
  } while (0)

#pragma unroll 1
  for (int pass = 0; pass < 2; pass++) {
    const unsigned short* Bpw =
        Bp + ((size_t)(pass * 32 + w * 4) * 32) * 512 + l * 8;

    // prologue: stage chunk 0
    SLOAD(0);
    SWRITE(0, 0, pass == 0);
    LOADB(bC, 0);
    __syncthreads();

#pragma unroll 1
    for (int kc = 0; kc < 16; kc++) {
      const int bufofs = (kc & 1) * ABUF_BYTES;
      if (kc < 15) SLOAD(kc + 1);
      LOADB(bN, kc * 2 + 1);
      LOADA(bufofs, 0);
      MF(bC);
      LOADB(bC, (kc * 2 + 2) & 31);
      LOADA(bufofs, 1);
      MF(bN);
      if (kc < 15) {
        SWRITE(((kc + 1) & 1) * ABUF_BYTES, kc + 1, pass == 0);
        __syncthreads();
      }
    }

    if (pass == 0) {
      // ---- pass-0 epilogue: bias, partial SS, raw store, sparse ----
      float bv[4];
#pragma unroll
      for (int j = 0; j < 4; j++) bv[j] = bias[w * 64 + j * 16 + ml];
#pragma unroll
      for (int i = 0; i < 8; i++) {
#pragma unroll
        for (int r = 0; r < 4; r++) {
          float ss = 0.f;
#pragma unroll
          for (int j = 0; j < 4; j++) {
            acc[i][j][r] += bv[j];
            const float x = acc[i][j][r];
            ss = fmaf(x, x, ss);
          }
          ss += __shfl_xor(ss, 1); ss += __shfl_xor(ss, 2);
          ss += __shfl_xor(ss, 4); ss += __shfl_xor(ss, 8);
          if (ml == 0) redLDS[(i * 16 + q * 4 + r) * 8 + w] = ss;
        }
      }
      __syncthreads();
      if (t < 128) {
        float v = 0.f;
#pragma unroll
        for (int p = 0; p < 8; p++) v += redLDS[t * 8 + p];
        ssLDS[t] = v;
      }
      // raw (unnormalized) store of cols 0..511
#pragma unroll
      for (int i = 0; i < 8; i++) {
#pragma unroll
        for (int r = 0; r < 4; r++) {
          const int row = i * 16 + q * 4 + r;
          const int gm = mBase + row;
          const int s = gm & (SEQ - 1);
          if (s != 0) {
            const int b = gm >> 11;
            float* orow = out + COLBERT_OFF + (size_t)(b * (SEQ - 1) + s - 1) * HDIM;
#pragma unroll
            for (int j = 0; j < 4; j++)
              orow[w * 64 + j * 16 + ml] = acc[i][j][r];
          }
        }
      }
      // sparse head finalize
      {
        float d = dot;
        d += __shfl_xor(d, 1); d += __shfl_xor(d, 2);
        if (sseg == 0) {
          const float wgt = d + sparse_b[0];
          if (wgt > 0.f) {
            const int gm = mBase + srow;
            const int id = input_ids[gm];
            if (id > 3) {
              atomicMax((int*)(out + SPARSE_OFF + (size_t)(gm >> 11) * VOCAB + id),
                        __float_as_int(wgt));
            }
          }
        }
      }
      // reset accumulators for pass 1
#pragma unroll
      for (int i = 0; i < 8; i++)
#pragma unroll
        for (int j = 0; j < 4; j++) acc[i][j] = (f32x4){0.f, 0.f, 0.f, 0.f};
      __syncthreads();
    } else {
      // ---- pass-1 epilogue: total SS, inv, normalized store, fix half0 ----
      float bv[4];
#pragma unroll
      for (int j = 0; j < 4; j++) bv[j] = bias[512 + w * 64 + j * 16 + ml];
#pragma unroll
      for (int i = 0; i < 8; i++) {
#pragma unroll
        for (int r = 0; r < 4; r++) {
          float ss = 0.f;
#pragma unroll
          for (int j = 0; j < 4; j++) {
            acc[i][j][r] += bv[j];
            const float x = acc[i][j][r];
            ss = fmaf(x, x, ss);
          }
          ss += __shfl_xor(ss, 1); ss += __shfl_xor(ss, 2);
          ss += __shfl_xor(ss, 4); ss += __shfl_xor(ss, 8);
          if (ml == 0) redLDS[(i * 16 + q * 4 + r) * 8 + w] = ss;
        }
      }
      __syncthreads();
      if (t < 128) {
        float v = ssLDS[t];
#pragma unroll
        for (int p = 0; p < 8; p++) v += redLDS[t * 8 + p];
        const int gm = mBase + t;
        const int s = gm & (SEQ - 1), b = gm >> 11;
        const float mval = mask[b * SEQ + s];
        // x*mval / max(|mval|*||x||, eps)
        invLDS[t] = mval / fmaxf(fabsf(mval) * sqrtf(v), 1e-12f);
      }
      __syncthreads();
      // store cols 512..1023 normalized
#pragma unroll
      for (int i = 0; i < 8; i++) {
#pragma unroll
        for (int r = 0; r < 4; r++) {
          const int row = i * 16 + q * 4 + r;
          const int gm = mBase + row;
          const int s = gm & (SEQ - 1);
          if (s != 0) {
            const int b = gm >> 11;
            float* orow = out + COLBERT_OFF + (size_t)(b * (SEQ - 1) + s - 1) * HDIM;
            const float iv = invLDS[row];
#pragma unroll
            for (int j = 0; j < 4; j++)
              orow[512 + w * 64 + j * 16 + ml] = acc[i][j][r] * iv;
          }
        }
      }
      // fix cols 0..511 (written raw by this same block in pass 0)
#pragma unroll 1
      for (int k2 = 0; k2 < 32; k2++) {
        const int idx = k2 * 512 + t;        // 128 rows x 128 f32x4
        const int row = idx >> 7, c4 = idx & 127;
        const int gm = mBase + row;
        const int s = gm & (SEQ - 1);
        if (s != 0) {
          const int b = gm >> 11;
          f32x4* p = (f32x4*)(out + COLBERT_OFF +
                              (size_t)(b * (SEQ - 1) + s - 1) * HDIM) + c4;
          const float iv = invLDS[row];
          f32x4 vv = *p;
          vv.x *= iv; vv.y *= iv; vv.z *= iv; vv.w *= iv;
          *p = vv;
        }
      }
    }
  }
}

// ---------------------------------------------------------------------------
extern "C" void kernel_launch(void* const* d_in, const int* in_sizes, int n_in,
                              void* d_out, int out_size, void* d_ws, size_t ws_size,
                              hipStream_t stream) {
  (void)in_sizes; (void)n_in; (void)out_size; (void)ws_size;
  const float* hidden = (const float*)d_in[0];
  const float* attn_mask = (const float*)d_in[1];
  const int* input_ids = (const int*)d_in[2];
  const float* sparse_W = (const float*)d_in[3];
  const float* sparse_b = (const float*)d_in[4];
  const float* colbert_W = (const float*)d_in[5];
  const float* colbert_b = (const float*)d_in[6];
  float* out = (float*)d_out;

  unsigned short* Wt = (unsigned short*)d_ws;   // 2 MiB packed bf16 weights

  prep_kernel<<<1552, 256, 0, stream>>>(colbert_W, Wt, out, hidden);
  fused_kernel<<<M_TOT / 128, 512, FUSED_LDS, stream>>>(
      hidden, Wt, colbert_b, attn_mask, sparse_W, sparse_b, input_ids, out);
}